// Round 7
// baseline (37.370 us; speedup 1.0000x reference)
//
#include <hip/hip_runtime.h>
#include <hip/hip_fp16.h>
#include <math.h>

// T=24, NSEQ=16384, FS=64, FM=16, FC=16 -> I=96; H=32.
//
// All-in-wave MFMA GRU (swapped operands, D[gate_row][seq]):
//  - wave owns 16 seqs x ALL 96 gate rows (6 row tiles) -> h' recurrence is
//    100% in-register: no LDS, no barriers, no cross-lane ops.
//    sigma k-permutation (validated r3-r6): lane's 8 computed h' are exactly
//    its own B-fragment slots.
//  - Critical-path minimization:
//    * h-side hi/lo bf16 terms -> TWO PARALLEL accumulators (MFMA dep depth 2,
//      was 4-6), combined by one f32x4 add per tile.
//    * x-side (f16 single-term) for step t+1 computed during step t
//      (h-independent) -> h-chain starts from ready C operand.
//    * x prefetched 3 steps deep in registers.
//    * biases packed as f32 blob -> 8 float4 loads, short prologue.
//  - grid 256 blocks x 256 thr = 1024 independent waves (1/SIMD).

typedef __attribute__((ext_vector_type(8))) short short8;
typedef __attribute__((ext_vector_type(8))) _Float16 half8;
typedef __attribute__((ext_vector_type(4))) float f32x4;

#define NSEQ 16384
#define TSTEPS 24
#define LOG2E 1.44269504088896340736f

// ws layout (ushort units)
#define P_HH_HI 0        // [96][32] bf16-hi, scaled, sigma-k
#define P_HH_LO 3072
#define P_MC    6144     // [96][32] f16, scaled, natural k (met|ctx)
#define P_SP    9216     // [96][64] f16, scaled (spatial)
#define P_WP_HI 15360    // [64][32] bf16-hi, Wp^T sigma-k (unscaled)
#define P_WP_LO 17408
#define P_BIAS  19456    // 128 f32: [96] acc-bias scaled, [32] bhn scaled

__device__ __forceinline__ unsigned short bf16_rn(float x) {
  unsigned u = __float_as_uint(x);
  u += 0x7FFFu + ((u >> 16) & 1u);
  return (unsigned short)(u >> 16);
}
__device__ __forceinline__ int sigma_inv(int ks) {
  int cc = ks >> 3, e = ks & 7;
  return (e < 4) ? (4 * cc + e) : (16 + 4 * cc + (e - 4));
}

__global__ void pack_w(const float* __restrict__ W_ih,
                       const float* __restrict__ W_hh,
                       const float* __restrict__ b_ih,
                       const float* __restrict__ b_hh,
                       const float* __restrict__ Wp,
                       unsigned short* __restrict__ ws) {
  int idx = blockIdx.x * blockDim.x + threadIdx.x;
  for (int i = idx; i < 14464; i += gridDim.x * blockDim.x) {
    if (i < 3072) {                       // W_hh bf16 hi/lo, scaled, sigma-k
      int row = i >> 5, ks = i & 31;
      float sc = (row < 64) ? LOG2E : (2.0f * LOG2E);
      float v = W_hh[row * 32 + sigma_inv(ks)] * sc;
      unsigned short h = bf16_rn(v);
      float hf = __uint_as_float(((unsigned)h) << 16);
      ws[P_HH_HI + i] = h;
      ws[P_HH_LO + i] = bf16_rn(v - hf);
    } else if (i < 6144) {                // W_ih cols 64..95 -> f16 scaled
      int j = i - 3072;
      int row = j >> 5, k = j & 31;
      float sc = (row < 64) ? LOG2E : (2.0f * LOG2E);
      ws[P_MC + j] = __half_as_ushort(__float2half(W_ih[row * 96 + 64 + k] * sc));
    } else if (i < 12288) {               // W_ih cols 0..63 -> f16 scaled
      int j = i - 6144;
      int row = j >> 6, k = j & 63;
      float sc = (row < 64) ? LOG2E : (2.0f * LOG2E);
      ws[P_SP + j] = __half_as_ushort(__float2half(W_ih[row * 96 + k] * sc));
    } else if (i < 14336) {               // Wp^T bf16 hi/lo, sigma-k
      int j = i - 12288;
      int frow = j >> 5, ks = j & 31;
      float v = Wp[sigma_inv(ks) * 64 + frow];
      unsigned short h = bf16_rn(v);
      float hf = __uint_as_float(((unsigned)h) << 16);
      ws[P_WP_HI + j] = h;
      ws[P_WP_LO + j] = bf16_rn(v - hf);
    } else {                              // f32 bias blob
      int k = i - 14336;
      float* bb = (float*)(ws + P_BIAS);
      if (k < 96) {
        float sc = (k < 64) ? LOG2E : (2.0f * LOG2E);
        bb[k] = (b_ih[k] + (k < 64 ? b_hh[k] : 0.0f)) * sc;
      } else {
        int u = k - 96;
        bb[k] = 2.0f * LOG2E * b_hh[64 + u];
      }
    }
  }
}

__device__ __forceinline__ float exp2_fast(float x) {
#if __has_builtin(__builtin_amdgcn_exp2f)
  return __builtin_amdgcn_exp2f(x);
#else
  return __expf(x * 0.6931471805599453f);
#endif
}

__device__ __forceinline__ unsigned int pk_f16(float a, float b) {
#if __has_builtin(__builtin_amdgcn_cvt_pkrtz)
  auto r = __builtin_amdgcn_cvt_pkrtz(a, b);   // __fp16 ext_vector(2)
  return __builtin_bit_cast(unsigned int, r);
#else
  return (unsigned)__half_as_ushort(__float2half(a)) |
         ((unsigned)__half_as_ushort(__float2half(b)) << 16);
#endif
}

__device__ __forceinline__ f32x4 mfma_bf(short8 a, short8 b, f32x4 c) {
  return __builtin_amdgcn_mfma_f32_16x16x32_bf16(a, b, c, 0, 0, 0);
}
__device__ __forceinline__ f32x4 mfma_h(half8 a, half8 b, f32x4 c) {
  return __builtin_amdgcn_mfma_f32_16x16x32_f16(a, b, c, 0, 0, 0);
}

union S8u { short8 v; unsigned int u[4]; };
union H8u { half8 v; unsigned int u[4]; };

__global__ __launch_bounds__(256, 1)
void gru3(const float* __restrict__ spatial,
          const float* __restrict__ met,
          const float* __restrict__ ctx,
          const unsigned short* __restrict__ ws,
          float* __restrict__ out) {
  const int tid = threadIdx.x;
  const int lane = tid & 63;
  const int wv = tid >> 6;       // wave 0..3, independent
  const int l15 = lane & 15;
  const int c = lane >> 4;       // 0..3
  const int seq = blockIdx.x * 64 + wv * 16 + l15;

  // ---- persistent weights: all 6 row tiles ----
  short8 whh_hi[6], whh_lo[6];
  half8 wmc[6];
#pragma unroll
  for (int j = 0; j < 6; ++j) {
    int off = (j * 16 + l15) * 32 + c * 8;
    whh_hi[j] = *(const short8*)(ws + P_HH_HI + off);
    whh_lo[j] = *(const short8*)(ws + P_HH_LO + off);
    S8u t; t.v = *(const short8*)(ws + P_MC + off);
    H8u h; h.u[0] = t.u[0]; h.u[1] = t.u[1]; h.u[2] = t.u[2]; h.u[3] = t.u[3];
    wmc[j] = h.v;
  }

  // ---- bias init via f32 blob (float4 loads) ----
  const float* bb = (const float*)(ws + P_BIAS);
  f32x4 acc_i[6], bhnA, bhnB;
#pragma unroll
  for (int j = 0; j < 6; ++j) {
    float4 v = *(const float4*)(bb + j * 16 + 4 * c);
    acc_i[j][0] = v.x; acc_i[j][1] = v.y; acc_i[j][2] = v.z; acc_i[j][3] = v.w;
  }
  {
    float4 va = *(const float4*)(bb + 96 + 4 * c);
    float4 vb = *(const float4*)(bb + 96 + 16 + 4 * c);
    bhnA[0] = va.x; bhnA[1] = va.y; bhnA[2] = va.z; bhnA[3] = va.w;
    bhnB[0] = vb.x; bhnB[1] = vb.y; bhnB[2] = vb.z; bhnB[3] = vb.w;
  }

  // ---- fold spatial (time-invariant) into acc_i, f16 single-term ----
#pragma unroll
  for (int kt = 0; kt < 2; ++kt) {
    const float* sp = spatial + (size_t)seq * 64 + kt * 32 + c * 8;
    float4 a0 = *(const float4*)sp;
    float4 a1 = *(const float4*)(sp + 4);
    H8u sf;
    sf.u[0] = pk_f16(a0.x, a0.y); sf.u[1] = pk_f16(a0.z, a0.w);
    sf.u[2] = pk_f16(a1.x, a1.y); sf.u[3] = pk_f16(a1.z, a1.w);
#pragma unroll
    for (int j = 0; j < 6; ++j) {
      int row = j * 16 + l15;
      S8u t; t.v = *(const short8*)(ws + P_SP + row * 64 + kt * 32 + c * 8);
      H8u wv2; wv2.u[0] = t.u[0]; wv2.u[1] = t.u[1]; wv2.u[2] = t.u[2]; wv2.u[3] = t.u[3];
      acc_i[j] = mfma_h(wv2.v, sf.v, acc_i[j]);
    }
  }

  // ---- x prefetch: per lane 8 floats/step; 3 steps deep ----
  const float* lptr = ((c < 2) ? met : ctx) + (size_t)seq * 16 + (c & 1) * 8;
  float4 x0a = *(const float4*)lptr;
  float4 x0b = *(const float4*)(lptr + 4);
  float4 x1a = *(const float4*)(lptr + (size_t)1 * NSEQ * 16);
  float4 x1b = *(const float4*)(lptr + (size_t)1 * NSEQ * 16 + 4);
  float4 x2a = *(const float4*)(lptr + (size_t)2 * NSEQ * 16);
  float4 x2b = *(const float4*)(lptr + (size_t)2 * NSEQ * 16 + 4);
  float4 x3a = *(const float4*)(lptr + (size_t)3 * NSEQ * 16);
  float4 x3b = *(const float4*)(lptr + (size_t)3 * NSEQ * 16 + 4);

  // xacc(0) = bias + spatial + Wmc*x(0)
  f32x4 xacc[6];
  {
    H8u xf;
    xf.u[0] = pk_f16(x0a.x, x0a.y); xf.u[1] = pk_f16(x0a.z, x0a.w);
    xf.u[2] = pk_f16(x0b.x, x0b.y); xf.u[3] = pk_f16(x0b.z, x0b.w);
#pragma unroll
    for (int j = 0; j < 6; ++j) xacc[j] = mfma_h(wmc[j], xf.v, acc_i[j]);
  }

  float hst[8];
#pragma unroll
  for (int i = 0; i < 8; ++i) hst[i] = 0.0f;
  S8u fhi, flo;
#pragma unroll
  for (int i = 0; i < 4; ++i) { fhi.u[i] = 0u; flo.u[i] = 0u; }
  const f32x4 zero4 = {0.f, 0.f, 0.f, 0.f};

#pragma unroll 1
  for (int t = 0; t < TSTEPS; ++t) {
    // save n-tile input parts before xacc is recomputed
    f32x4 ti0 = xacc[4], ti1 = xacc[5];

    // h-side: hi-term and lo-term in PARALLEL accumulators (dep depth 2)
    f32x4 hi0 = mfma_bf(whh_hi[0], fhi.v, xacc[0]);
    f32x4 hi1 = mfma_bf(whh_hi[1], fhi.v, xacc[1]);
    f32x4 hi2 = mfma_bf(whh_hi[2], fhi.v, xacc[2]);
    f32x4 hi3 = mfma_bf(whh_hi[3], fhi.v, xacc[3]);
    f32x4 hi4 = mfma_bf(whh_hi[4], fhi.v, bhnA);
    f32x4 hi5 = mfma_bf(whh_hi[5], fhi.v, bhnB);
    f32x4 lo0 = mfma_bf(whh_lo[0], fhi.v, zero4);
    f32x4 lo1 = mfma_bf(whh_lo[1], fhi.v, zero4);
    f32x4 lo2 = mfma_bf(whh_lo[2], fhi.v, zero4);
    f32x4 lo3 = mfma_bf(whh_lo[3], fhi.v, zero4);
    f32x4 lo4 = mfma_bf(whh_lo[4], fhi.v, zero4);
    f32x4 lo5 = mfma_bf(whh_lo[5], fhi.v, zero4);
    lo0 = mfma_bf(whh_hi[0], flo.v, lo0);
    lo1 = mfma_bf(whh_hi[1], flo.v, lo1);
    lo2 = mfma_bf(whh_hi[2], flo.v, lo2);
    lo3 = mfma_bf(whh_hi[3], flo.v, lo3);
    lo4 = mfma_bf(whh_hi[4], flo.v, lo4);
    lo5 = mfma_bf(whh_hi[5], flo.v, lo5);

    // x-side for t+1 (h-independent, off critical path)
    {
      H8u xf;
      xf.u[0] = pk_f16(x1a.x, x1a.y); xf.u[1] = pk_f16(x1a.z, x1a.w);
      xf.u[2] = pk_f16(x1b.x, x1b.y); xf.u[3] = pk_f16(x1b.z, x1b.w);
#pragma unroll
      for (int j = 0; j < 6; ++j) xacc[j] = mfma_h(wmc[j], xf.v, acc_i[j]);
    }
    // rotate x regs; issue load of x(t+4)
    x1a = x2a; x1b = x2b; x2a = x3a; x2b = x3b;
    {
      int tf = (t + 4 < TSTEPS) ? (t + 4) : (TSTEPS - 1);
      x3a = *(const float4*)(lptr + (size_t)tf * NSEQ * 16);
      x3b = *(const float4*)(lptr + (size_t)tf * NSEQ * 16 + 4);
    }

    // combine + gates for 8 units (i = jj*4+q)
    unsigned int hi_[8], lo_[8];
#pragma unroll
    for (int jj = 0; jj < 2; ++jj) {
      f32x4 ddr = (jj == 0) ? (hi0 + lo0) : (hi1 + lo1);
      f32x4 ddz = (jj == 0) ? (hi2 + lo2) : (hi3 + lo3);
      f32x4 tth = (jj == 0) ? (hi4 + lo4) : (hi5 + lo5);
      f32x4 tti = (jj == 0) ? ti0 : ti1;
#pragma unroll
      for (int q = 0; q < 4; ++q) {
        int i = jj * 4 + q;
        float r = __builtin_amdgcn_rcpf(1.0f + exp2_fast(-ddr[q]));
        float z = __builtin_amdgcn_rcpf(1.0f + exp2_fast(-ddz[q]));
        float Y = fmaf(r, tth[q], tti[q]);
        float e = exp2_fast(-Y);
        float nn = fmaf(2.0f, __builtin_amdgcn_rcpf(1.0f + e), -1.0f);
        float hv = fmaf(z, hst[i] - nn, nn);
        hst[i] = hv;
        unsigned u = __float_as_uint(hv);
        hi_[i] = u >> 16;                                  // bf16 hi (trunc)
        float hf = __uint_as_float(u & 0xFFFF0000u);
        lo_[i] = __float_as_uint(hv - hf) >> 16;           // bf16 lo
      }
    }
    fhi.u[0] = hi_[0] | (hi_[1] << 16); fhi.u[1] = hi_[2] | (hi_[3] << 16);
    fhi.u[2] = hi_[4] | (hi_[5] << 16); fhi.u[3] = hi_[6] | (hi_[7] << 16);
    flo.u[0] = lo_[0] | (lo_[1] << 16); flo.u[1] = lo_[2] | (lo_[3] << 16);
    flo.u[2] = lo_[4] | (lo_[5] << 16); flo.u[3] = lo_[6] | (lo_[7] << 16);
  }

  // ---- projection: out^T[f][seq] = WpT (sigma-k) x h-fragment ----
#pragma unroll
  for (int p = 0; p < 4; ++p) {
    int off = (p * 16 + l15) * 32 + c * 8;
    short8 wph = *(const short8*)(ws + P_WP_HI + off);
    short8 wpl = *(const short8*)(ws + P_WP_LO + off);
    f32x4 o = mfma_bf(wph, fhi.v, zero4);
    o = mfma_bf(wpl, fhi.v, o);
    o = mfma_bf(wph, flo.v, o);
    float* op = out + (size_t)seq * 64 + p * 16 + 4 * c;
    *(float4*)op = make_float4(o[0], o[1], o[2], o[3]);
  }
}

extern "C" void kernel_launch(void* const* d_in, const int* in_sizes, int n_in,
                              void* d_out, int out_size, void* d_ws, size_t ws_size,
                              hipStream_t stream) {
  const float* spatial = (const float*)d_in[0];
  const float* met     = (const float*)d_in[1];
  const float* ctx     = (const float*)d_in[2];
  const float* W_ih    = (const float*)d_in[3];
  const float* W_hh    = (const float*)d_in[4];
  const float* b_ih    = (const float*)d_in[5];
  const float* b_hh    = (const float*)d_in[6];
  const float* Wp      = (const float*)d_in[7];
  float* out = (float*)d_out;
  unsigned short* ws = (unsigned short*)d_ws;

  hipLaunchKernelGGL(pack_w, dim3(57), dim3(256), 0, stream,
                     W_ih, W_hh, b_ih, b_hh, Wp, ws);
  hipLaunchKernelGGL(gru3, dim3(256), dim3(256), 0, stream,
                     spatial, met, ctx, ws, out);
}

// Round 8
// 26.733 us; speedup vs baseline: 1.3979x; 1.3979x over previous
//
#include <hip/hip_runtime.h>
#include <hip/hip_fp16.h>
#include <math.h>

// T=24, NSEQ=16384, FS=64, FM=16, FC=16 -> I=96; H=32.
//
// R8: R6 structure (2-wave unit-split, 2 waves/SIMD, raw lgkm barrier) with
// SINGLE-TERM f16 h (h in [-1,1]: f16 2^-11 rel > bf16-hi precision).
// Per wave per step: 3 f16 h-MFMAs + 3 f16 x-MFMAs (for t+1, h-independent),
// no hi/lo split, uint2 h-exchange, rotation-free 2-step x prefetch.
// sigma k-permutation (validated R3-R6 for bf16; f16 fragment has identical
// 8-elem/4-VGPR structure): lane's 4 computed h' are its own B-slots,
// partner's 4 via LDS uint2 + 1 barrier/step.

typedef __attribute__((ext_vector_type(8))) short short8;
typedef __attribute__((ext_vector_type(8))) _Float16 half8;
typedef __attribute__((ext_vector_type(4))) float f32x4;

#define NSEQ 16384
#define TSTEPS 24
#define LOG2E 1.44269504088896340736f

// ws layout (ushort units)
#define P_HH   0        // [96][32] f16, scaled, sigma-k
#define P_MC   3072     // [96][32] f16, scaled, natural k (met|ctx)
#define P_SP   6144     // [96][64] f16, scaled (spatial)
#define P_WP_H 12288    // [64][32] f16 hi, Wp^T sigma-k
#define P_WP_L 14336    // [64][32] f16 lo
#define P_BIAS 16384    // 128 f32: [96] acc-bias scaled, [32] bhn scaled

__device__ __forceinline__ int sigma_inv(int ks) {
  int cc = ks >> 3, e = ks & 7;
  return (e < 4) ? (4 * cc + e) : (16 + 4 * cc + (e - 4));
}

__global__ void pack_w(const float* __restrict__ W_ih,
                       const float* __restrict__ W_hh,
                       const float* __restrict__ b_ih,
                       const float* __restrict__ b_hh,
                       const float* __restrict__ Wp,
                       unsigned short* __restrict__ ws) {
  int idx = blockIdx.x * blockDim.x + threadIdx.x;
  for (int i = idx; i < 14464; i += gridDim.x * blockDim.x) {
    if (i < 3072) {                       // W_hh f16, scaled, sigma-k
      int row = i >> 5, ks = i & 31;
      float sc = (row < 64) ? LOG2E : (2.0f * LOG2E);
      float v = W_hh[row * 32 + sigma_inv(ks)] * sc;
      ws[P_HH + i] = __half_as_ushort(__float2half(v));
    } else if (i < 6144) {                // W_ih cols 64..95 -> f16 scaled
      int j = i - 3072;
      int row = j >> 5, k = j & 31;
      float sc = (row < 64) ? LOG2E : (2.0f * LOG2E);
      ws[P_MC + j] = __half_as_ushort(__float2half(W_ih[row * 96 + 64 + k] * sc));
    } else if (i < 12288) {               // W_ih cols 0..63 -> f16 scaled
      int j = i - 6144;
      int row = j >> 6, k = j & 63;
      float sc = (row < 64) ? LOG2E : (2.0f * LOG2E);
      ws[P_SP + j] = __half_as_ushort(__float2half(W_ih[row * 96 + k] * sc));
    } else if (i < 14336) {               // Wp^T f16 hi/lo, sigma-k
      int j = i - 12288;
      int frow = j >> 5, ks = j & 31;
      float v = Wp[sigma_inv(ks) * 64 + frow];
      __half h = __float2half(v);
      float lo = v - __half2float(h);
      ws[P_WP_H + j] = __half_as_ushort(h);
      ws[P_WP_L + j] = __half_as_ushort(__float2half(lo));
    } else {                              // f32 bias blob
      int k = i - 14336;
      float* bb = (float*)(ws + P_BIAS);
      if (k < 96) {
        float sc = (k < 64) ? LOG2E : (2.0f * LOG2E);
        bb[k] = (b_ih[k] + (k < 64 ? b_hh[k] : 0.0f)) * sc;
      } else {
        bb[k] = 2.0f * LOG2E * b_hh[64 + (k - 96)];
      }
    }
  }
}

__device__ __forceinline__ float exp2_fast(float x) {
#if __has_builtin(__builtin_amdgcn_exp2f)
  return __builtin_amdgcn_exp2f(x);
#else
  return __expf(x * 0.6931471805599453f);
#endif
}

__device__ __forceinline__ unsigned int pk_f16(float a, float b) {
#if __has_builtin(__builtin_amdgcn_cvt_pkrtz)
  auto r = __builtin_amdgcn_cvt_pkrtz(a, b);   // __fp16 ext_vector(2)
  return __builtin_bit_cast(unsigned int, r);
#else
  return (unsigned)__half_as_ushort(__float2half(a)) |
         ((unsigned)__half_as_ushort(__float2half(b)) << 16);
#endif
}

__device__ __forceinline__ f32x4 mfma_h(half8 a, half8 b, f32x4 c) {
  return __builtin_amdgcn_mfma_f32_16x16x32_f16(a, b, c, 0, 0, 0);
}

// workgroup barrier draining LDS ops only — global prefetch stays in flight
__device__ __forceinline__ void barrier_lds() {
  asm volatile("s_waitcnt lgkmcnt(0)" ::: "memory");
  __builtin_amdgcn_s_barrier();
}

union S8u { short8 v; unsigned int u[4]; };
union H8u { half8 v; unsigned int u[4]; };

__global__ __launch_bounds__(128, 2)
void gru4(const float* __restrict__ spatial,
          const float* __restrict__ met,
          const float* __restrict__ ctx,
          const unsigned short* __restrict__ ws,
          float* __restrict__ out) {
  __shared__ unsigned int hbuf[2][2][64][2];  // [buf][wave][lane][2 dwords f16x4]

  const int tid = threadIdx.x;
  const int lane = tid & 63;
  const int p = tid >> 6;            // wave 0/1 in the pair
  const int l15 = lane & 15;
  const int c = lane >> 4;           // 0..3
  const int seq = blockIdx.x * 16 + l15;

  // zero initial-h buffer (read at t=0 from hbuf[1])
  ((unsigned int*)hbuf[1])[tid] = 0u;
  ((unsigned int*)hbuf[1])[tid + 128] = 0u;

  // ---- persistent weights: 3 row tiles (r,z,n) for units 16p..16p+16 ----
  half8 whh[3], wmc[3];
#pragma unroll
  for (int g = 0; g < 3; ++g) {
    int off = (g * 32 + p * 16 + l15) * 32 + c * 8;
    S8u t0; t0.v = *(const short8*)(ws + P_HH + off);
    H8u h0; h0.u[0]=t0.u[0]; h0.u[1]=t0.u[1]; h0.u[2]=t0.u[2]; h0.u[3]=t0.u[3];
    whh[g] = h0.v;
    S8u t1; t1.v = *(const short8*)(ws + P_MC + off);
    H8u h1; h1.u[0]=t1.u[0]; h1.u[1]=t1.u[1]; h1.u[2]=t1.u[2]; h1.u[3]=t1.u[3];
    wmc[g] = h1.v;
  }

  // ---- bias init via f32 blob ----
  const float* bb = (const float*)(ws + P_BIAS);
  f32x4 acc_i[3], bhn4;
#pragma unroll
  for (int g = 0; g < 3; ++g) {
    float4 v = *(const float4*)(bb + g * 32 + p * 16 + 4 * c);
    acc_i[g][0] = v.x; acc_i[g][1] = v.y; acc_i[g][2] = v.z; acc_i[g][3] = v.w;
  }
  {
    float4 v = *(const float4*)(bb + 96 + p * 16 + 4 * c);
    bhn4[0] = v.x; bhn4[1] = v.y; bhn4[2] = v.z; bhn4[3] = v.w;
  }

  // ---- fold spatial (time-invariant) into acc_i, f16 single-term ----
#pragma unroll
  for (int kt = 0; kt < 2; ++kt) {
    const float* sp = spatial + (size_t)seq * 64 + kt * 32 + c * 8;
    float4 a0 = *(const float4*)sp;
    float4 a1 = *(const float4*)(sp + 4);
    H8u sf;
    sf.u[0] = pk_f16(a0.x, a0.y); sf.u[1] = pk_f16(a0.z, a0.w);
    sf.u[2] = pk_f16(a1.x, a1.y); sf.u[3] = pk_f16(a1.z, a1.w);
#pragma unroll
    for (int g = 0; g < 3; ++g) {
      int row = g * 32 + p * 16 + l15;
      S8u t; t.v = *(const short8*)(ws + P_SP + row * 64 + kt * 32 + c * 8);
      H8u wv; wv.u[0]=t.u[0]; wv.u[1]=t.u[1]; wv.u[2]=t.u[2]; wv.u[3]=t.u[3];
      acc_i[g] = mfma_h(wv.v, sf.v, acc_i[g]);
    }
  }

  // ---- x: per-lane direct loads; rotation-free parity-slot prefetch ----
  const float* lptr = ((c < 2) ? met : ctx) + (size_t)seq * 16 + (c & 1) * 8;

  // xacc(0) = bias + spatial + Wmc*x(0)
  f32x4 xacc[3];
  {
    float4 a0 = *(const float4*)lptr;
    float4 a1 = *(const float4*)(lptr + 4);
    H8u xf;
    xf.u[0] = pk_f16(a0.x, a0.y); xf.u[1] = pk_f16(a0.z, a0.w);
    xf.u[2] = pk_f16(a1.x, a1.y); xf.u[3] = pk_f16(a1.z, a1.w);
#pragma unroll
    for (int g = 0; g < 3; ++g) xacc[g] = mfma_h(wmc[g], xf.v, acc_i[g]);
  }
  // slot s holds x(t+1) for the next step with (t+1 parity): s = t&1
  float4 xs0a = *(const float4*)(lptr + (size_t)1 * NSEQ * 16);
  float4 xs0b = *(const float4*)(lptr + (size_t)1 * NSEQ * 16 + 4);
  float4 xs1a = *(const float4*)(lptr + (size_t)2 * NSEQ * 16);
  float4 xs1b = *(const float4*)(lptr + (size_t)2 * NSEQ * 16 + 4);

  float hst[4] = {0.f, 0.f, 0.f, 0.f};
  unsigned int own0 = 0u, own1 = 0u;
  const f32x4 zero4 = {0.f, 0.f, 0.f, 0.f};

  barrier_lds();

#pragma unroll 2
  for (int t = 0; t < TSTEPS; ++t) {
    // partner h' from previous step
    const unsigned int* hp = &hbuf[(t + 1) & 1][1 - p][lane][0];
    unsigned int phx = hp[0], phy = hp[1];

    // merged h fragment: wave p's units occupy dwords 2p,2p+1
    H8u fh;
    fh.u[0] = p ? phx : own0;  fh.u[1] = p ? phy : own1;
    fh.u[2] = p ? own0 : phx;  fh.u[3] = p ? own1 : phy;

    // h-side MFMAs (C = precomputed input-part accumulators)
    f32x4 d0 = mfma_h(whh[0], fh.v, xacc[0]);   // r
    f32x4 d1 = mfma_h(whh[1], fh.v, xacc[1]);   // z
    f32x4 dn = mfma_h(whh[2], fh.v, bhn4);      // gh_n + b_hn
    f32x4 ti = xacc[2];                         // gi_n (saved)

    // x-side for t+1 (h-independent): consume slot t&1, refill with x(t+3)
    {
      float4 xa = (t & 1) ? xs1a : xs0a;
      float4 xb = (t & 1) ? xs1b : xs0b;
      H8u xf;
      xf.u[0] = pk_f16(xa.x, xa.y); xf.u[1] = pk_f16(xa.z, xa.w);
      xf.u[2] = pk_f16(xb.x, xb.y); xf.u[3] = pk_f16(xb.z, xb.w);
#pragma unroll
      for (int g = 0; g < 3; ++g) xacc[g] = mfma_h(wmc[g], xf.v, acc_i[g]);
      int tf = (t + 3 < TSTEPS) ? (t + 3) : (TSTEPS - 1);
      float4 na = *(const float4*)(lptr + (size_t)tf * NSEQ * 16);
      float4 nb = *(const float4*)(lptr + (size_t)tf * NSEQ * 16 + 4);
      if (t & 1) { xs1a = na; xs1b = nb; } else { xs0a = na; xs0b = nb; }
    }

    // gates (weights pre-scaled by log2e / 2log2e); tanh = 2*rcp(1+exp2(-Y))-1
    float hv_[4];
#pragma unroll
    for (int q = 0; q < 4; ++q) {
      float r = __builtin_amdgcn_rcpf(1.0f + exp2_fast(-d0[q]));
      float z = __builtin_amdgcn_rcpf(1.0f + exp2_fast(-d1[q]));
      float Y = fmaf(r, dn[q], ti[q]);
      float e = exp2_fast(-Y);
      float nn = fmaf(2.0f, __builtin_amdgcn_rcpf(1.0f + e), -1.0f);
      float hv = fmaf(z, hst[q] - nn, nn);
      hst[q] = hv;
      hv_[q] = hv;
    }
    own0 = pk_f16(hv_[0], hv_[1]);
    own1 = pk_f16(hv_[2], hv_[3]);
    hbuf[t & 1][p][lane][0] = own0;
    hbuf[t & 1][p][lane][1] = own1;

    barrier_lds();
  }

  // ---- final h fragment (t=23 wrote hbuf[1], barrier done) ----
  H8u fh;
  {
    const unsigned int* hp = &hbuf[1][1 - p][lane][0];
    unsigned int phx = hp[0], phy = hp[1];
    fh.u[0] = p ? phx : own0;  fh.u[1] = p ? phy : own1;
    fh.u[2] = p ? own0 : phx;  fh.u[3] = p ? own1 : phy;
  }

  // ---- projection: wave p does f-tiles {p, 2+p}, f16 2-term ----
#pragma unroll
  for (int pt = 0; pt < 2; ++pt) {
    int ftile = pt * 2 + p;
    int off = (ftile * 16 + l15) * 32 + c * 8;
    S8u t0; t0.v = *(const short8*)(ws + P_WP_H + off);
    H8u wph; wph.u[0]=t0.u[0]; wph.u[1]=t0.u[1]; wph.u[2]=t0.u[2]; wph.u[3]=t0.u[3];
    S8u t1; t1.v = *(const short8*)(ws + P_WP_L + off);
    H8u wpl; wpl.u[0]=t1.u[0]; wpl.u[1]=t1.u[1]; wpl.u[2]=t1.u[2]; wpl.u[3]=t1.u[3];
    f32x4 o = mfma_h(wph.v, fh.v, zero4);
    o = mfma_h(wpl.v, fh.v, o);
    float* op = out + (size_t)seq * 64 + ftile * 16 + 4 * c;
    *(float4*)op = make_float4(o[0], o[1], o[2], o[3]);
  }
}

extern "C" void kernel_launch(void* const* d_in, const int* in_sizes, int n_in,
                              void* d_out, int out_size, void* d_ws, size_t ws_size,
                              hipStream_t stream) {
  const float* spatial = (const float*)d_in[0];
  const float* met     = (const float*)d_in[1];
  const float* ctx     = (const float*)d_in[2];
  const float* W_ih    = (const float*)d_in[3];
  const float* W_hh    = (const float*)d_in[4];
  const float* b_ih    = (const float*)d_in[5];
  const float* b_hh    = (const float*)d_in[6];
  const float* Wp      = (const float*)d_in[7];
  float* out = (float*)d_out;
  unsigned short* ws = (unsigned short*)d_ws;

  hipLaunchKernelGGL(pack_w, dim3(57), dim3(256), 0, stream,
                     W_ih, W_hh, b_ih, b_hh, Wp, ws);
  hipLaunchKernelGGL(gru4, dim3(1024), dim3(128), 0, stream,
                     spatial, met, ctx, ws, out);
}

// Round 9
// 26.270 us; speedup vs baseline: 1.4225x; 1.0176x over previous
//
#include <hip/hip_runtime.h>
#include <hip/hip_fp16.h>
#include <math.h>

// T=24, NSEQ=16384, FS=64, FM=16, FC=16 -> I=96; H=32.
//
// R9: producer/consumer wave specialization, 4 waves/block, 16 seqs/block,
// 1024 blocks -> 4096 waves = 4/SIMD (2x R8 stream count per SIMD).
//  - waves 0,1 (CONSUMER, unit-split p): serial recurrence only.
//    Per step: read xacc C-tiles from LDS, 3 f16 h-MFMAs, gates, uint2
//    h-exchange (R8 scheme: sigma layout keeps own 4 h' in-register).
//  - waves 2,3 (PRODUCER, unit-half q): xacc(t+1)=bias+spatial+Wmc*x(t+1)
//    (h-independent), 3 f16 MFMAs + global x loads, ds_write_b128 into
//    double-buffered LDS tiles. Producer D-layout == consumer C-layout
//    (same (l15,c) lane mapping) -> no transpose.
//  - xls[buf][tile][seq16][20-pad f32]: 16B-aligned b128 both sides,
//    row stride 80B -> banks spread, ~2-way (free).
//  - One lgkm-only barrier/step (global loads stay in flight).
//  - Parity discipline: producer writes buf (t+1)&1 while consumer reads
//    buf t&1; hbuf ping-pong as R8. All waves hit 25 barriers total.

typedef __attribute__((ext_vector_type(8))) short short8;
typedef __attribute__((ext_vector_type(8))) _Float16 half8;
typedef __attribute__((ext_vector_type(4))) float f32x4;

#define NSEQ 16384
#define TSTEPS 24
#define LOG2E 1.44269504088896340736f

// ws layout (ushort units)
#define P_HH   0        // [96][32] f16, scaled, sigma-k
#define P_MC   3072     // [96][32] f16, scaled, natural k (met|ctx)
#define P_SP   6144     // [96][64] f16, scaled (spatial)
#define P_WP_H 12288    // [64][32] f16 hi, Wp^T sigma-k
#define P_WP_L 14336    // [64][32] f16 lo
#define P_BIAS 16384    // 128 f32: [96] acc-bias scaled, [32] bhn scaled

__device__ __forceinline__ int sigma_inv(int ks) {
  int cc = ks >> 3, e = ks & 7;
  return (e < 4) ? (4 * cc + e) : (16 + 4 * cc + (e - 4));
}

__global__ void pack_w(const float* __restrict__ W_ih,
                       const float* __restrict__ W_hh,
                       const float* __restrict__ b_ih,
                       const float* __restrict__ b_hh,
                       const float* __restrict__ Wp,
                       unsigned short* __restrict__ ws) {
  int idx = blockIdx.x * blockDim.x + threadIdx.x;
  for (int i = idx; i < 14464; i += gridDim.x * blockDim.x) {
    if (i < 3072) {                       // W_hh f16, scaled, sigma-k
      int row = i >> 5, ks = i & 31;
      float sc = (row < 64) ? LOG2E : (2.0f * LOG2E);
      float v = W_hh[row * 32 + sigma_inv(ks)] * sc;
      ws[P_HH + i] = __half_as_ushort(__float2half(v));
    } else if (i < 6144) {                // W_ih cols 64..95 -> f16 scaled
      int j = i - 3072;
      int row = j >> 5, k = j & 31;
      float sc = (row < 64) ? LOG2E : (2.0f * LOG2E);
      ws[P_MC + j] = __half_as_ushort(__float2half(W_ih[row * 96 + 64 + k] * sc));
    } else if (i < 12288) {               // W_ih cols 0..63 -> f16 scaled
      int j = i - 6144;
      int row = j >> 6, k = j & 63;
      float sc = (row < 64) ? LOG2E : (2.0f * LOG2E);
      ws[P_SP + j] = __half_as_ushort(__float2half(W_ih[row * 96 + k] * sc));
    } else if (i < 14336) {               // Wp^T f16 hi/lo, sigma-k
      int j = i - 12288;
      int frow = j >> 5, ks = j & 31;
      float v = Wp[sigma_inv(ks) * 64 + frow];
      __half h = __float2half(v);
      float lo = v - __half2float(h);
      ws[P_WP_H + j] = __half_as_ushort(h);
      ws[P_WP_L + j] = __half_as_ushort(__float2half(lo));
    } else {                              // f32 bias blob
      int k = i - 14336;
      float* bb = (float*)(ws + P_BIAS);
      if (k < 96) {
        float sc = (k < 64) ? LOG2E : (2.0f * LOG2E);
        bb[k] = (b_ih[k] + (k < 64 ? b_hh[k] : 0.0f)) * sc;
      } else {
        bb[k] = 2.0f * LOG2E * b_hh[64 + (k - 96)];
      }
    }
  }
}

__device__ __forceinline__ float exp2_fast(float x) {
#if __has_builtin(__builtin_amdgcn_exp2f)
  return __builtin_amdgcn_exp2f(x);
#else
  return __expf(x * 0.6931471805599453f);
#endif
}

__device__ __forceinline__ unsigned int pk_f16(float a, float b) {
#if __has_builtin(__builtin_amdgcn_cvt_pkrtz)
  auto r = __builtin_amdgcn_cvt_pkrtz(a, b);   // __fp16 ext_vector(2)
  return __builtin_bit_cast(unsigned int, r);
#else
  return (unsigned)__half_as_ushort(__float2half(a)) |
         ((unsigned)__half_as_ushort(__float2half(b)) << 16);
#endif
}

__device__ __forceinline__ f32x4 mfma_h(half8 a, half8 b, f32x4 c) {
  return __builtin_amdgcn_mfma_f32_16x16x32_f16(a, b, c, 0, 0, 0);
}

// workgroup barrier draining LDS ops only — global prefetch stays in flight
__device__ __forceinline__ void barrier_lds() {
  asm volatile("s_waitcnt lgkmcnt(0)" ::: "memory");
  __builtin_amdgcn_s_barrier();
}

union S8u { short8 v; unsigned int u[4]; };
union H8u { half8 v; unsigned int u[4]; };

__global__ __launch_bounds__(256, 4)
void gru5(const float* __restrict__ spatial,
          const float* __restrict__ met,
          const float* __restrict__ ctx,
          const unsigned short* __restrict__ ws,
          float* __restrict__ out) {
  // xacc tiles: [buf][tile(gate*2+half)][seq 16][20-pad f32]
  __shared__ float xls[2][6][16][20];
  __shared__ unsigned int hbuf[2][2][64][2];

  const int tid = threadIdx.x;
  const int lane = tid & 63;
  const int wv = tid >> 6;       // 0,1 consumer; 2,3 producer
  const int l15 = lane & 15;
  const int c = lane >> 4;       // 0..3
  const int seq = blockIdx.x * 16 + l15;
  const float* bb = (const float*)(ws + P_BIAS);
  const f32x4 zero4 = {0.f, 0.f, 0.f, 0.f};

  // zero initial-h buffer (hbuf[1] = 256 dwords; one per thread)
  ((unsigned int*)hbuf[1])[tid] = 0u;

  if (wv >= 2) {
    // ======================= PRODUCER =======================
    const int q = wv - 2;            // unit-half
    half8 wmc[3];
    f32x4 acc_i[3];
#pragma unroll
    for (int g = 0; g < 3; ++g) {
      int off = (g * 32 + q * 16 + l15) * 32 + c * 8;
      S8u t1; t1.v = *(const short8*)(ws + P_MC + off);
      H8u h1; h1.u[0]=t1.u[0]; h1.u[1]=t1.u[1]; h1.u[2]=t1.u[2]; h1.u[3]=t1.u[3];
      wmc[g] = h1.v;
      float4 v = *(const float4*)(bb + g * 32 + q * 16 + 4 * c);
      acc_i[g][0] = v.x; acc_i[g][1] = v.y; acc_i[g][2] = v.z; acc_i[g][3] = v.w;
    }
    // fold spatial (time-invariant)
#pragma unroll
    for (int kt = 0; kt < 2; ++kt) {
      const float* sp = spatial + (size_t)seq * 64 + kt * 32 + c * 8;
      float4 a0 = *(const float4*)sp;
      float4 a1 = *(const float4*)(sp + 4);
      H8u sf;
      sf.u[0] = pk_f16(a0.x, a0.y); sf.u[1] = pk_f16(a0.z, a0.w);
      sf.u[2] = pk_f16(a1.x, a1.y); sf.u[3] = pk_f16(a1.z, a1.w);
#pragma unroll
      for (int g = 0; g < 3; ++g) {
        int row = g * 32 + q * 16 + l15;
        S8u t; t.v = *(const short8*)(ws + P_SP + row * 64 + kt * 32 + c * 8);
        H8u w2; w2.u[0]=t.u[0]; w2.u[1]=t.u[1]; w2.u[2]=t.u[2]; w2.u[3]=t.u[3];
        acc_i[g] = mfma_h(w2.v, sf.v, acc_i[g]);
      }
    }
    const float* lptr = ((c < 2) ? met : ctx) + (size_t)seq * 16 + (c & 1) * 8;
    // xacc(0) -> buffer 0
    {
      float4 a0 = *(const float4*)lptr;
      float4 a1 = *(const float4*)(lptr + 4);
      H8u xf;
      xf.u[0] = pk_f16(a0.x, a0.y); xf.u[1] = pk_f16(a0.z, a0.w);
      xf.u[2] = pk_f16(a1.x, a1.y); xf.u[3] = pk_f16(a1.z, a1.w);
#pragma unroll
      for (int g = 0; g < 3; ++g) {
        f32x4 D = mfma_h(wmc[g], xf.v, acc_i[g]);
        *(f32x4*)&xls[0][g * 2 + q][l15][c * 4] = D;
      }
    }
    // parity slots: slot s holds x(t+1) for step t with t&1==s
    float4 xs0a = *(const float4*)(lptr + (size_t)1 * NSEQ * 16);
    float4 xs0b = *(const float4*)(lptr + (size_t)1 * NSEQ * 16 + 4);
    float4 xs1a = *(const float4*)(lptr + (size_t)2 * NSEQ * 16);
    float4 xs1b = *(const float4*)(lptr + (size_t)2 * NSEQ * 16 + 4);

    barrier_lds();

#pragma unroll 2
    for (int t = 0; t < TSTEPS; ++t) {
      float4 xa = (t & 1) ? xs1a : xs0a;
      float4 xb = (t & 1) ? xs1b : xs0b;
      H8u xf;
      xf.u[0] = pk_f16(xa.x, xa.y); xf.u[1] = pk_f16(xa.z, xa.w);
      xf.u[2] = pk_f16(xb.x, xb.y); xf.u[3] = pk_f16(xb.z, xb.w);
      // refill slot with x(t+3) (used at step t+2)
      {
        int tf = (t + 3 < TSTEPS) ? (t + 3) : (TSTEPS - 1);
        float4 na = *(const float4*)(lptr + (size_t)tf * NSEQ * 16);
        float4 nb = *(const float4*)(lptr + (size_t)tf * NSEQ * 16 + 4);
        if (t & 1) { xs1a = na; xs1b = nb; } else { xs0a = na; xs0b = nb; }
      }
      const int buf = (t + 1) & 1;
#pragma unroll
      for (int g = 0; g < 3; ++g) {
        f32x4 D = mfma_h(wmc[g], xf.v, acc_i[g]);
        *(f32x4*)&xls[buf][g * 2 + q][l15][c * 4] = D;
      }
      barrier_lds();
    }
    // producers done (no epilogue)
  } else {
    // ======================= CONSUMER =======================
    const int p = wv;                // unit-half
    half8 whh[3];
#pragma unroll
    for (int g = 0; g < 3; ++g) {
      int off = (g * 32 + p * 16 + l15) * 32 + c * 8;
      S8u t0; t0.v = *(const short8*)(ws + P_HH + off);
      H8u h0; h0.u[0]=t0.u[0]; h0.u[1]=t0.u[1]; h0.u[2]=t0.u[2]; h0.u[3]=t0.u[3];
      whh[g] = h0.v;
    }
    f32x4 bhn4;
    {
      float4 v = *(const float4*)(bb + 96 + p * 16 + 4 * c);
      bhn4[0] = v.x; bhn4[1] = v.y; bhn4[2] = v.z; bhn4[3] = v.w;
    }
    float hst[4] = {0.f, 0.f, 0.f, 0.f};
    unsigned int own0 = 0u, own1 = 0u;

    barrier_lds();

#pragma unroll 2
    for (int t = 0; t < TSTEPS; ++t) {
      // partner h' + xacc C-tiles (all LDS reads issued up front)
      const unsigned int* hp = &hbuf[(t + 1) & 1][1 - p][lane][0];
      unsigned int phx = hp[0], phy = hp[1];
      f32x4 xr = *(const f32x4*)&xls[t & 1][p][l15][c * 4];
      f32x4 xz = *(const f32x4*)&xls[t & 1][2 + p][l15][c * 4];
      f32x4 ti = *(const f32x4*)&xls[t & 1][4 + p][l15][c * 4];

      H8u fh;
      fh.u[0] = p ? phx : own0;  fh.u[1] = p ? phy : own1;
      fh.u[2] = p ? own0 : phx;  fh.u[3] = p ? own1 : phy;

      f32x4 d0 = mfma_h(whh[0], fh.v, xr);    // r
      f32x4 d1 = mfma_h(whh[1], fh.v, xz);    // z
      f32x4 dn = mfma_h(whh[2], fh.v, bhn4);  // gh_n + b_hn

      float hv_[4];
#pragma unroll
      for (int qq = 0; qq < 4; ++qq) {
        float r = __builtin_amdgcn_rcpf(1.0f + exp2_fast(-d0[qq]));
        float z = __builtin_amdgcn_rcpf(1.0f + exp2_fast(-d1[qq]));
        float Y = fmaf(r, dn[qq], ti[qq]);
        float e = exp2_fast(-Y);
        float nn = fmaf(2.0f, __builtin_amdgcn_rcpf(1.0f + e), -1.0f);
        float hv = fmaf(z, hst[qq] - nn, nn);
        hst[qq] = hv;
        hv_[qq] = hv;
      }
      own0 = pk_f16(hv_[0], hv_[1]);
      own1 = pk_f16(hv_[2], hv_[3]);
      hbuf[t & 1][p][lane][0] = own0;
      hbuf[t & 1][p][lane][1] = own1;

      barrier_lds();
    }

    // final h fragment (t=23 wrote hbuf[1], barrier done)
    H8u fh;
    {
      const unsigned int* hp = &hbuf[1][1 - p][lane][0];
      unsigned int phx = hp[0], phy = hp[1];
      fh.u[0] = p ? phx : own0;  fh.u[1] = p ? phy : own1;
      fh.u[2] = p ? own0 : phx;  fh.u[3] = p ? own1 : phy;
    }
    // projection: wave p does f-tiles {p, 2+p}, f16 2-term
#pragma unroll
    for (int pt = 0; pt < 2; ++pt) {
      int ftile = pt * 2 + p;
      int off = (ftile * 16 + l15) * 32 + c * 8;
      S8u t0; t0.v = *(const short8*)(ws + P_WP_H + off);
      H8u wph; wph.u[0]=t0.u[0]; wph.u[1]=t0.u[1]; wph.u[2]=t0.u[2]; wph.u[3]=t0.u[3];
      S8u t1; t1.v = *(const short8*)(ws + P_WP_L + off);
      H8u wpl; wpl.u[0]=t1.u[0]; wpl.u[1]=t1.u[1]; wpl.u[2]=t1.u[2]; wpl.u[3]=t1.u[3];
      f32x4 o = mfma_h(wph.v, fh.v, zero4);
      o = mfma_h(wpl.v, fh.v, o);
      float* op = out + (size_t)seq * 64 + ftile * 16 + 4 * c;
      *(float4*)op = make_float4(o[0], o[1], o[2], o[3]);
    }
  }
}

extern "C" void kernel_launch(void* const* d_in, const int* in_sizes, int n_in,
                              void* d_out, int out_size, void* d_ws, size_t ws_size,
                              hipStream_t stream) {
  const float* spatial = (const float*)d_in[0];
  const float* met     = (const float*)d_in[1];
  const float* ctx     = (const float*)d_in[2];
  const float* W_ih    = (const float*)d_in[3];
  const float* W_hh    = (const float*)d_in[4];
  const float* b_ih    = (const float*)d_in[5];
  const float* b_hh    = (const float*)d_in[6];
  const float* Wp      = (const float*)d_in[7];
  float* out = (float*)d_out;
  unsigned short* ws = (unsigned short*)d_ws;

  hipLaunchKernelGGL(pack_w, dim3(57), dim3(256), 0, stream,
                     W_ih, W_hh, b_ih, b_hh, Wp, ws);
  hipLaunchKernelGGL(gru5, dim3(1024), dim3(256), 0, stream,
                     spatial, met, ctx, ws, out);
}